// Round 16
// baseline (131.031 us; speedup 1.0000x reference)
//
#include <hip/hip_runtime.h>
#include <hip/hip_bf16.h>
#include <hip/hip_cooperative_groups.h>

namespace cg = cooperative_groups;

typedef __attribute__((ext_vector_type(8))) short short8;
typedef __attribute__((ext_vector_type(4))) float f32x4;

#define LDSW 136  // padded w1 row stride (bf16) = 272 B
#define NBLK 256  // 1 block/CU guaranteed: 16 waves<=32, LDS 44KB<=64KB, VGPR<=128 via bounds

// round-to-nearest-even f32 -> bf16
static __device__ __forceinline__ ushort f2bf(float f) {
  unsigned int u = __builtin_bit_cast(unsigned int, f);
  u += 0x7fffu + ((u >> 16) & 1u);
  return (ushort)(u >> 16);
}

// ---------------- COOPERATIVE fused: read x ONCE (held in bf16 regs), sync, gemm -----------
// R15 failed at launch: 625 blocks needed 3 blocks/CU co-residency the runtime wouldn't
// grant. v2 needs exactly 1 block/CU (guaranteed under any LDS-pool/VGPR assumption).
// 3125 tiles = 53 blocks x 13 + 203 x 12. Per pass 16 waves cover 4 tiles (wave w: tile
// p*4+(w>>2), rows (w&3)*16+c, cols kg*8 within each kb*32). Phase A: load f32, colsum in
// f32 (identical math to R10), convert to bf16 regs. ONE grid.sync. Pooled-reduce + t done
// redundantly per block. Phase B: MFMA from held regs, store out+t. HBM floor: x once
// (102.4R) + out once (102.4W) vs R10's ~254MB.
__global__ __launch_bounds__(1024) void fused_kernel(
    const float* __restrict__ x, ushort* __restrict__ w1p,
    const float* __restrict__ w1, const float* __restrict__ w2,
    const float* __restrict__ bias, float* __restrict__ out,
    float* __restrict__ partial, int n) {
  __shared__ ushort w1t[128 * LDSW];  // 34816 B
  __shared__ float scr[16 * 128];     // 8192 B: phase-A wave-partials, then pooled scratch
  __shared__ float pooled_lds[128];
  __shared__ float t_lds[128];

  cg::grid_group grid = cg::this_grid();
  int tid = threadIdx.x;
  int w = tid >> 6, lane = tid & 63;
  int c = lane & 15, kg = lane >> 4;
  int wt = w >> 2;   // tile-offset within a pass
  int wsr = w & 3;   // row-stripe within a tile
  int bid = blockIdx.x;
  int ntiles = 12 + (bid < 53 ? 1 : 0);
  int tile0 = bid * 12 + (bid < 53 ? bid : 53);

  // block 255: pack w1 f32 -> bf16 [col][k] padded, into ws (visible to all after grid.sync)
  if (bid == NBLK - 1) {
#pragma unroll
    for (int i = 0; i < 16; ++i) {
      int idx = tid + i * 1024;  // 16384 = 128*128
      int k = idx >> 7, cc = idx & 127;
      w1p[cc * LDSW + k] = f2bf(w1[k * 128 + cc]);
    }
  }

  // ---- phase A: load x (f32), accumulate colsum in f32, hold bf16 in regs ----
  short8 xa[4][4];  // [pass][kb]; inactive entries unused (guarded identically in phase B)
#pragma unroll
  for (int kb = 0; kb < 4; ++kb) {
    float cs8[8] = {0.f, 0.f, 0.f, 0.f, 0.f, 0.f, 0.f, 0.f};
#pragma unroll
    for (int p = 0; p < 4; ++p) {
      int lt = p * 4 + wt;
      if (lt < ntiles) {
        const float* ptr =
            x + ((size_t)(tile0 + lt) * 64 + wsr * 16 + c) * 128 + kb * 32 + kg * 8;
        float4 a0 = *reinterpret_cast<const float4*>(ptr);
        float4 a1 = *reinterpret_cast<const float4*>(ptr + 4);
        short8 f;
        f[0] = (short)f2bf(a0.x); f[1] = (short)f2bf(a0.y);
        f[2] = (short)f2bf(a0.z); f[3] = (short)f2bf(a0.w);
        f[4] = (short)f2bf(a1.x); f[5] = (short)f2bf(a1.y);
        f[6] = (short)f2bf(a1.z); f[7] = (short)f2bf(a1.w);
        xa[p][kb] = f;
        cs8[0] += a0.x; cs8[1] += a0.y; cs8[2] += a0.z; cs8[3] += a0.w;
        cs8[4] += a1.x; cs8[5] += a1.y; cs8[6] += a1.z; cs8[7] += a1.w;
      }
    }
    // butterfly over the 16 c-lanes (once per kb, outside the load loop)
#pragma unroll
    for (int m = 8; m >= 1; m >>= 1) {
#pragma unroll
      for (int j = 0; j < 8; ++j) cs8[j] += __shfl_xor(cs8[j], m, 16);
    }
    if (c == 0) {
#pragma unroll
      for (int j = 0; j < 8; ++j) scr[w * 128 + kb * 32 + kg * 8 + j] = cs8[j];
    }
  }
  __syncthreads();
  if (tid < 128) {
    float s = 0.f;
#pragma unroll
    for (int ww = 0; ww < 16; ++ww) s += scr[ww * 128 + tid];
    partial[(size_t)bid * 128 + tid] = s;
  }

  grid.sync();  // all partials visible device-wide; w1p packed

  // ---- stage w1t (needed only for phase B) ----
  {
    const ulonglong2* src = reinterpret_cast<const ulonglong2*>(w1p);
    ulonglong2* dst = reinterpret_cast<ulonglong2*>(w1t);
#pragma unroll
    for (int i = 0; i < 3; ++i) {
      int idx = tid + i * 1024;
      if (idx < 2176) dst[idx] = src[idx];
    }
  }
  // ---- pooled + t, redundantly per block (partial is 128KB, L2/L3-hot) ----
  {
    int col = tid & 127, g = tid >> 7;
    float s = 0.f;
#pragma unroll
    for (int k = 0; k < 32; ++k) s += partial[(size_t)(g + 8 * k) * 128 + col];
    scr[g * 128 + col] = s;  // scr's phase-A use finished before grid.sync
  }
  __syncthreads();
  if (tid < 128) {
    float p_ = 0.f;
#pragma unroll
    for (int g = 0; g < 8; ++g) p_ += scr[g * 128 + tid];
    pooled_lds[tid] = p_;
  }
  __syncthreads();
  if (tid < 128) {
    float a = 0.f;
#pragma unroll 8
    for (int i = 0; i < 128; ++i) a += pooled_lds[i] * w2[i * 128 + tid];
    t_lds[tid] = a / (float)n + bias[tid];
  }
  __syncthreads();  // t_lds ready; w1t staging (all threads) also complete

  // ---- phase B: MFMA from held registers, store out + t ----
#pragma unroll
  for (int p = 0; p < 4; ++p) {
    int lt = p * 4 + wt;
    if (lt < ntiles) {
      f32x4 acc[8];
#pragma unroll
      for (int nb = 0; nb < 8; ++nb) acc[nb] = (f32x4){0.f, 0.f, 0.f, 0.f};
#pragma unroll
      for (int kb = 0; kb < 4; ++kb) {
        int k0 = kb * 32 + kg * 8;
#pragma unroll
        for (int nb = 0; nb < 8; ++nb) {
          short8 bfrag = *reinterpret_cast<const short8*>(&w1t[(nb * 16 + c) * LDSW + k0]);
          acc[nb] = __builtin_amdgcn_mfma_f32_16x16x32_bf16(xa[p][kb], bfrag, acc[nb], 0, 0, 0);
        }
      }
      size_t rbase = (size_t)(tile0 + lt) * 64 + wsr * 16;
      // D layout (m89-verified): col = lane&15, row = (lane>>4)*4 + reg
#pragma unroll
      for (int nb = 0; nb < 8; ++nb) {
        int col = nb * 16 + c;
        float tv = t_lds[col];
#pragma unroll
        for (int i = 0; i < 4; ++i) {
          out[(rbase + kg * 4 + i) * 128 + col] = acc[nb][i] + tv;
        }
      }
    }
  }
}

extern "C" void kernel_launch(void* const* d_in, const int* in_sizes, int n_in,
                              void* d_out, int out_size, void* d_ws, size_t ws_size,
                              hipStream_t stream) {
  const float* x = (const float*)d_in[0];
  const float* w1 = (const float*)d_in[1];
  const float* w2 = (const float*)d_in[2];
  const float* bias = (const float*)d_in[3];
  float* out = (float*)d_out;
  int n = in_sizes[0] / 128;  // 200000

  char* ws = (char*)d_ws;
  ushort* w1p = (ushort*)ws;               // 34,816 B -> ends 34,816
  float* partial = (float*)(ws + 35328);   // 256*128*4 = 131,072 B (16B-aligned)

  void* kargs[] = {(void*)&x, (void*)&w1p, (void*)&w1, (void*)&w2,
                   (void*)&bias, (void*)&out, (void*)&partial, (void*)&n};
  hipLaunchCooperativeKernel((const void*)fused_kernel, dim3(NBLK), dim3(1024),
                             kargs, 0, stream);
}

// Round 17
// 102.268 us; speedup vs baseline: 1.2813x; 1.2813x over previous
//
#include <hip/hip_runtime.h>
#include <hip/hip_bf16.h>
#include <hip/hip_cooperative_groups.h>

namespace cg = cooperative_groups;

typedef __attribute__((ext_vector_type(8))) short short8;
typedef __attribute__((ext_vector_type(4))) float f32x4;

#define LDSW 136  // padded w1 row stride (bf16) = 272 B
#define NBLK 256  // 1 block/CU: 8 waves, VGPR<=256 (m69), LDS 40KB

// round-to-nearest-even f32 -> bf16
static __device__ __forceinline__ ushort f2bf(float f) {
  unsigned int u = __builtin_bit_cast(unsigned int, f);
  u += 0x7fffu + ((u >> 16) & 1u);
  return (ushort)(u >> 16);
}

// ---------------- COOPERATIVE fused v3: read x ONCE, hold bf16 in regs, sync, gemm ---------
// R16 failed by register spill: VGPR_Count=64 < xa's 112 -> scratch round-trip (150us).
// v3: 512-thr blocks + __launch_bounds__(512,2) -> VGPR cap 256, need ~185. 8 waves/CU,
// 1 block/CU guaranteed co-resident. 3125 tiles = 53x13 + 203x12; 2 tiles/pass; 7 passes.
// HBM floor: x once (102.4R) + out once (102.4W) vs split pipeline's ~254MB.
__global__ __launch_bounds__(512, 2) void fused_kernel(
    const float* __restrict__ x, ushort* __restrict__ w1p,
    const float* __restrict__ w1, const float* __restrict__ w2,
    const float* __restrict__ bias, float* __restrict__ out,
    float* __restrict__ partial, int n) {
  __shared__ ushort w1t[128 * LDSW];  // 34816 B
  __shared__ float scr[8 * 128];      // 4096 B
  __shared__ float pooled_lds[128];
  __shared__ float t_lds[128];

  cg::grid_group grid = cg::this_grid();
  int tid = threadIdx.x;
  int w = tid >> 6, lane = tid & 63;
  int c = lane & 15, kg = lane >> 4;
  int wt = w >> 2;   // which of the 2 tiles this pass
  int wsr = w & 3;   // 16-row stripe within the tile
  int bid = blockIdx.x;
  int ntiles = 12 + (bid < 53 ? 1 : 0);
  int tile0 = bid * 12 + (bid < 53 ? bid : 53);

  // block 255: pack w1 f32 -> bf16 [col][k] padded (visible to all after grid.sync)
  if (bid == NBLK - 1) {
#pragma unroll
    for (int i = 0; i < 32; ++i) {
      int idx = tid + i * 512;  // 16384 = 128*128
      int k = idx >> 7, cc = idx & 127;
      w1p[cc * LDSW + k] = f2bf(w1[k * 128 + cc]);
    }
  }

  // ---- phase A: load x (f32), colsum in f32 regs, hold bf16 regs ----
  short8 xa[7][4];  // 112 VGPRs — the point of launch_bounds(512,2)
#pragma unroll
  for (int kb = 0; kb < 4; ++kb) {
    float cs8[8] = {0.f, 0.f, 0.f, 0.f, 0.f, 0.f, 0.f, 0.f};
#pragma unroll
    for (int p = 0; p < 7; ++p) {
      int lt = p * 2 + wt;
      if (lt < ntiles) {
        const float* ptr =
            x + ((size_t)(tile0 + lt) * 64 + wsr * 16 + c) * 128 + kb * 32 + kg * 8;
        float4 a0 = *reinterpret_cast<const float4*>(ptr);
        float4 a1 = *reinterpret_cast<const float4*>(ptr + 4);
        short8 f;
        f[0] = (short)f2bf(a0.x); f[1] = (short)f2bf(a0.y);
        f[2] = (short)f2bf(a0.z); f[3] = (short)f2bf(a0.w);
        f[4] = (short)f2bf(a1.x); f[5] = (short)f2bf(a1.y);
        f[6] = (short)f2bf(a1.z); f[7] = (short)f2bf(a1.w);
        xa[p][kb] = f;
        cs8[0] += a0.x; cs8[1] += a0.y; cs8[2] += a0.z; cs8[3] += a0.w;
        cs8[4] += a1.x; cs8[5] += a1.y; cs8[6] += a1.z; cs8[7] += a1.w;
      }
    }
    // butterfly over the 16 c-lanes (once per kb, outside the load loop)
#pragma unroll
    for (int m = 8; m >= 1; m >>= 1) {
#pragma unroll
      for (int j = 0; j < 8; ++j) cs8[j] += __shfl_xor(cs8[j], m, 16);
    }
    if (c == 0) {
#pragma unroll
      for (int j = 0; j < 8; ++j) scr[w * 128 + kb * 32 + kg * 8 + j] = cs8[j];
    }
  }
  __syncthreads();
  if (tid < 128) {
    float s = 0.f;
#pragma unroll
    for (int ww = 0; ww < 8; ++ww) s += scr[ww * 128 + tid];
    partial[(size_t)bid * 128 + tid] = s;
  }

  grid.sync();  // partials visible device-wide; w1p packed

  // ---- stage w1t ----
  {
    const ulonglong2* src = reinterpret_cast<const ulonglong2*>(w1p);
    ulonglong2* dst = reinterpret_cast<ulonglong2*>(w1t);
#pragma unroll
    for (int i = 0; i < 5; ++i) {
      int idx = tid + i * 512;
      if (idx < 2176) dst[idx] = src[idx];
    }
  }
  // ---- pooled + t, redundantly per block (partial = 128KB, L2/L3-hot) ----
  {
    int col = tid & 127, g = tid >> 7;  // g 0..3
    float s = 0.f;
#pragma unroll 8
    for (int k = 0; k < 64; ++k) s += partial[(size_t)(g + 4 * k) * 128 + col];
    scr[g * 128 + col] = s;  // scr phase-A use finished pre-sync
  }
  __syncthreads();
  if (tid < 128) {
    float p_ = scr[tid] + scr[128 + tid] + scr[256 + tid] + scr[384 + tid];
    pooled_lds[tid] = p_;
  }
  __syncthreads();
  if (tid < 128) {
    float a = 0.f;
#pragma unroll 8
    for (int i = 0; i < 128; ++i) a += pooled_lds[i] * w2[i * 128 + tid];
    t_lds[tid] = a / (float)n + bias[tid];
  }
  __syncthreads();  // t_lds + w1t ready

  // ---- phase B: MFMA from held regs, store out + t ----
#pragma unroll
  for (int p = 0; p < 7; ++p) {
    int lt = p * 2 + wt;
    if (lt < ntiles) {
      f32x4 acc[8];
#pragma unroll
      for (int nb = 0; nb < 8; ++nb) acc[nb] = (f32x4){0.f, 0.f, 0.f, 0.f};
#pragma unroll
      for (int kb = 0; kb < 4; ++kb) {
        int k0 = kb * 32 + kg * 8;
#pragma unroll
        for (int nb = 0; nb < 8; ++nb) {
          short8 bfrag = *reinterpret_cast<const short8*>(&w1t[(nb * 16 + c) * LDSW + k0]);
          acc[nb] = __builtin_amdgcn_mfma_f32_16x16x32_bf16(xa[p][kb], bfrag, acc[nb], 0, 0, 0);
        }
      }
      size_t rbase = (size_t)(tile0 + lt) * 64 + wsr * 16;
      // D layout (m89-verified): col = lane&15, row = (lane>>4)*4 + reg
#pragma unroll
      for (int nb = 0; nb < 8; ++nb) {
        int col = nb * 16 + c;
        float tv = t_lds[col];
#pragma unroll
        for (int i = 0; i < 4; ++i) {
          out[(rbase + kg * 4 + i) * 128 + col] = acc[nb][i] + tv;
        }
      }
    }
  }
}

extern "C" void kernel_launch(void* const* d_in, const int* in_sizes, int n_in,
                              void* d_out, int out_size, void* d_ws, size_t ws_size,
                              hipStream_t stream) {
  const float* x = (const float*)d_in[0];
  const float* w1 = (const float*)d_in[1];
  const float* w2 = (const float*)d_in[2];
  const float* bias = (const float*)d_in[3];
  float* out = (float*)d_out;
  int n = in_sizes[0] / 128;  // 200000

  char* ws = (char*)d_ws;
  ushort* w1p = (ushort*)ws;               // 34,816 B
  float* partial = (float*)(ws + 35328);   // 256*128*4 = 131,072 B

  void* kargs[] = {(void*)&x, (void*)&w1p, (void*)&w1, (void*)&w2,
                   (void*)&bias, (void*)&out, (void*)&partial, (void*)&n};
  hipLaunchCooperativeKernel((const void*)fused_kernel, dim3(NBLK), dim3(512),
                             kargs, 0, stream);
}

// Round 18
// 73.090 us; speedup vs baseline: 1.7927x; 1.3992x over previous
//
#include <hip/hip_runtime.h>
#include <hip/hip_bf16.h>

typedef __attribute__((ext_vector_type(8))) short short8;
typedef __attribute__((ext_vector_type(4))) float f32x4;
typedef unsigned int u32;

#define LDSW 136       // padded w1 row stride (bf16) = 272 B
#define CS_BLOCKS 3125 // 64-row tiles
#define PK_BLOCKS 64   // pack_w1 folded into the colsum grid

// round-to-nearest-even f32 -> bf16
static __device__ __forceinline__ ushort f2bf(float f) {
  unsigned int u = __builtin_bit_cast(unsigned int, f);
  u += 0x7fffu + ((u >> 16) & 1u);
  return (ushort)(u >> 16);
}

// ---------------- kernel 1: colsum via global_load_lds  (+ pack_w1 folded in) --------------
// Rate table (R2-R17, replay-delta evidence): VGPR-load cold read 1.7-2.6 TB/s;
// global_load_lds cold read 3.3 (this kernel, 31us); L3-warm 6-7; write 7.1. This kernel is
// AT its read ceiling. Blocks >= CS_BLOCKS do the w1 pack instead (saves one launch).
__global__ __launch_bounds__(256) void colsum_pack_kernel(const float* __restrict__ x,
                                                          const float* __restrict__ w1,
                                                          ushort* __restrict__ w1p,
                                                          float4* __restrict__ partial4) {
  __shared__ float tile[8192];     // 32 KB: 64 rows x 128 cols
  __shared__ float4 red[8][32];    // 4 KB
  int tid = threadIdx.x;

  if (blockIdx.x >= CS_BLOCKS) {  // pack path: 64 blocks x 256 = 16384 = 128*128
    int idx = (blockIdx.x - CS_BLOCKS) * 256 + tid;
    int k = idx >> 7, c = idx & 127;
    w1p[c * LDSW + k] = f2bf(w1[k * 128 + c]);
    return;
  }

  int lane = tid & 63;
  int wave = tid >> 6;
  const float* gbase = x + (size_t)blockIdx.x * 8192 + (size_t)(wave * 8) * 256 + lane * 4;
  float* lbase = tile + (wave * 8) * 256;  // wave-uniform
#pragma unroll
  for (int i = 0; i < 8; ++i) {
    __builtin_amdgcn_global_load_lds(
        (const __attribute__((address_space(1))) u32*)(gbase + i * 256),
        (__attribute__((address_space(3))) u32*)(lbase + i * 256), 16, 0, 0);
  }
  __syncthreads();  // vmcnt drain: tile complete

  int c4 = tid & 31;
  int rg = tid >> 5;
  const float4* tile4 = reinterpret_cast<const float4*>(tile);
  float4 acc = {0.f, 0.f, 0.f, 0.f};
#pragma unroll
  for (int k = 0; k < 8; ++k) {
    float4 v = tile4[(rg + 8 * k) * 32 + c4];
    acc.x += v.x; acc.y += v.y; acc.z += v.z; acc.w += v.w;
  }
  red[rg][c4] = acc;
  __syncthreads();
  if (tid < 32) {
    float4 s = red[0][tid];
#pragma unroll
    for (int g = 1; g < 8; ++g) {
      float4 v = red[g][tid];
      s.x += v.x; s.y += v.y; s.z += v.z; s.w += v.w;
    }
    partial4[(size_t)blockIdx.x * 32 + tid] = s;
  }
}

// ---------------- kernel 2: reduce partial[3125][128] -> partial2[128][128] ----------------
__global__ __launch_bounds__(256) void reduce_kernel(const float* __restrict__ partial,
                                                     float* __restrict__ partial2,
                                                     int nb) {
  int tid = threadIdx.x;
  int j = tid & 127;
  int orow = blockIdx.x * 2 + (tid >> 7);
  float s = 0.f;
  for (int r = orow; r < nb; r += 128) s += partial[(size_t)r * 128 + j];
  partial2[orow * 128 + j] = s;
}

// ---------------- kernel 3: t = (pooled @ w2)/n + bias  (1 block x 1024 thr) ---------------
__global__ __launch_bounds__(1024) void transmit_kernel(const float* __restrict__ partial,
                                                        const float* __restrict__ w2,
                                                        const float* __restrict__ bias,
                                                        float* __restrict__ t, int n,
                                                        int nblocks) {
  __shared__ float red[8][128];
  __shared__ float pooled[128];
  int tid = threadIdx.x;
  int j = tid & 127;
  int g = tid >> 7;

  float s = 0.f;
  for (int b = g; b < nblocks; b += 8) s += partial[b * 128 + j];
  red[g][j] = s;
  __syncthreads();
  if (tid < 128) {
    float p = 0.f;
#pragma unroll
    for (int gg = 0; gg < 8; ++gg) p += red[gg][j];
    pooled[j] = p;
  }
  __syncthreads();

  float acc = 0.f;
#pragma unroll
  for (int ii = 0; ii < 16; ++ii) {
    int i = g * 16 + ii;
    acc += pooled[i] * w2[i * 128 + j];
  }
  __syncthreads();
  red[g][j] = acc;
  __syncthreads();
  if (tid < 128) {
    float a = 0.f;
#pragma unroll
    for (int gg = 0; gg < 8; ++gg) a += red[gg][j];
    t[j] = a / (float)n + bias[j];
  }
}

// ---------------- kernel 4: out = x @ w1 + t, x staged via global_load_lds -----------------
// P3: gemm's ~50MB L3-miss refill now rides the proven-fast gload_lds path (3.3 TB/s) instead
// of the 1.7-2.6 VGPR path. A-frag LDS reads are 16-way bank-conflicted (lanes 0-15 hit the
// same bank: row*128 % 32 == 0) but consume budget at 5.69x penalty (~9 TB/s chip) >> read
// supply (~6) — hidden under staging. LDS 68KB -> 2 blocks/CU.
__global__ __launch_bounds__(256) void gemm_lds_kernel(const float* __restrict__ x,
                                                       const ushort* __restrict__ w1p,
                                                       const float* __restrict__ tvec,
                                                       float* __restrict__ out) {
  __shared__ ushort w1t[128 * LDSW];  // 34816 B
  __shared__ float xt[8192];          // 32768 B: 64 rows x 128 cols
  __shared__ float t_lds[128];
  int tid = threadIdx.x;
  int lane = tid & 63;
  int wave = tid >> 6;

  // stage packed w1 (L2-hot) via VGPR copies
  {
    const ulonglong2* src = reinterpret_cast<const ulonglong2*>(w1p);
    ulonglong2* dst = reinterpret_cast<ulonglong2*>(w1t);
#pragma unroll
    for (int i = 0; i < 9; ++i) {
      int idx = tid + i * 256;
      if (idx < 2176) dst[idx] = src[idx];
    }
  }
  if (tid < 128) t_lds[tid] = tvec[tid];

  // stage x-tile via gload_lds (fast read path)
  {
    const float* gbase = x + (size_t)blockIdx.x * 8192 + (size_t)(wave * 8) * 256 + lane * 4;
    float* lbase = xt + (wave * 8) * 256;  // wave-uniform
#pragma unroll
    for (int i = 0; i < 8; ++i) {
      __builtin_amdgcn_global_load_lds(
          (const __attribute__((address_space(1))) u32*)(gbase + i * 256),
          (__attribute__((address_space(3))) u32*)(lbase + i * 256), 16, 0, 0);
    }
  }
  __syncthreads();  // drains both w1t loads and gload_lds

  int c = lane & 15;    // A row-in-tile / B col / D col
  int kg = lane >> 4;   // k-group 0..3
  int row = wave * 16 + c;
  int rbase = blockIdx.x * 64 + wave * 16;

  f32x4 acc[8];
#pragma unroll
  for (int nb = 0; nb < 8; ++nb) acc[nb] = (f32x4){0.f, 0.f, 0.f, 0.f};

#pragma unroll
  for (int kb = 0; kb < 4; ++kb) {
    int k0 = kb * 32 + kg * 8;
    float4 a0 = *reinterpret_cast<const float4*>(&xt[row * 128 + k0]);
    float4 a1 = *reinterpret_cast<const float4*>(&xt[row * 128 + k0 + 4]);
    short8 afrag;
    afrag[0] = (short)f2bf(a0.x);
    afrag[1] = (short)f2bf(a0.y);
    afrag[2] = (short)f2bf(a0.z);
    afrag[3] = (short)f2bf(a0.w);
    afrag[4] = (short)f2bf(a1.x);
    afrag[5] = (short)f2bf(a1.y);
    afrag[6] = (short)f2bf(a1.z);
    afrag[7] = (short)f2bf(a1.w);
#pragma unroll
    for (int nb = 0; nb < 8; ++nb) {
      short8 bfrag = *reinterpret_cast<const short8*>(&w1t[(nb * 16 + c) * LDSW + k0]);
      acc[nb] = __builtin_amdgcn_mfma_f32_16x16x32_bf16(afrag, bfrag, acc[nb], 0, 0, 0);
    }
  }

  // D layout (m89-verified): col = lane&15, row = (lane>>4)*4 + reg
#pragma unroll
  for (int nb = 0; nb < 8; ++nb) {
    int col = nb * 16 + c;
    float tv = t_lds[col];
#pragma unroll
    for (int i = 0; i < 4; ++i) {
      out[(size_t)(rbase + kg * 4 + i) * 128 + col] = acc[nb][i] + tv;
    }
  }
}

extern "C" void kernel_launch(void* const* d_in, const int* in_sizes, int n_in,
                              void* d_out, int out_size, void* d_ws, size_t ws_size,
                              hipStream_t stream) {
  const float* x = (const float*)d_in[0];
  const float* w1 = (const float*)d_in[1];
  const float* w2 = (const float*)d_in[2];
  const float* bias = (const float*)d_in[3];
  float* out = (float*)d_out;
  int n = in_sizes[0] / 128;  // 200000
  int nb = n / 64;            // 3125

  char* ws = (char*)d_ws;
  float* t = (float*)ws;                     // 512 B
  ushort* w1p = (ushort*)(ws + 512);         // 34,816 B -> ends 35,328
  float* partial = (float*)(ws + 35328);     // 3125*128*4 = 1,600,000 B -> ends 1,635,328
  float* partial2 = (float*)(ws + 1635328);  // 65,536 B

  hipLaunchKernelGGL(colsum_pack_kernel, dim3(nb + PK_BLOCKS), dim3(256), 0, stream,
                     x, w1, w1p, (float4*)partial);
  hipLaunchKernelGGL(reduce_kernel, dim3(64), dim3(256), 0, stream, partial, partial2, nb);
  hipLaunchKernelGGL(transmit_kernel, dim3(1), dim3(1024), 0, stream,
                     partial2, w2, bias, t, n, 128);
  hipLaunchKernelGGL(gemm_lds_kernel, dim3(nb), dim3(256), 0, stream, x, w1p, t, out);
}